// Round 17
// baseline (105.972 us; speedup 1.0000x reference)
//
#include <hip/hip_runtime.h>
#include <hip/hip_bf16.h>
#include <stdint.h>

#define SEQ 4096
#define DIN 1024
#define DOUT 1024

typedef __bf16 bf16;
typedef __bf16 bf16x4v __attribute__((ext_vector_type(4)));
typedef __bf16 bf16x8v __attribute__((ext_vector_type(8)));
typedef float f32x4 __attribute__((ext_vector_type(4)));

#define AS1 __attribute__((address_space(1)))
#define AS3 __attribute__((address_space(3)))

__device__ __forceinline__ void load_lds16(const void* g, void* l) {
  __builtin_amdgcn_global_load_lds((const AS1 uint32_t*)g, (AS3 uint32_t*)l, 16, 0, 0);
}

__device__ __forceinline__ int imin(int a, int b) { return a < b ? a : b; }

// m204 bijective XCD swizzle
__device__ __forceinline__ int xcd_swz(int orig, int nwg) {
  const int q = nwg >> 3, r = nwg & 7;
  const int x = orig & 7, idx = orig >> 3;
  return (x < r ? x * (q + 1) : r * (q + 1) + (x - r) * q) + idx;
}

// ---------------- fused cast fp32 -> bf16, 8 elems/thread (exact 1D grid) -----
// x: 2048 blocks; Wq/Wk/Wv: 512 each -> grid 3584.
__global__ __launch_bounds__(256) void cast_all_kernel(
    const float* __restrict__ x, const float* __restrict__ wq,
    const float* __restrict__ wk, const float* __restrict__ wv,
    bf16* __restrict__ xb, bf16* __restrict__ wqb,
    bf16* __restrict__ wkb, bf16* __restrict__ wvb) {
  const int id = blockIdx.x;
  const float* in; bf16* out; int blk;
  if (id < 2048) {
    in = x; out = xb; blk = id;
  } else {
    const int w = (id - 2048) >> 9;
    blk = (id - 2048) & 511;
    in = (w == 0) ? wq : (w == 1) ? wk : wv;
    out = (w == 0) ? wqb : (w == 1) ? wkb : wvb;
  }
  const int i = (blk * 256 + threadIdx.x) * 8;
  float4 v0 = *reinterpret_cast<const float4*>(in + i);
  float4 v1 = *reinterpret_cast<const float4*>(in + i + 4);
  bf16x8v o;
  o[0] = (bf16)v0.x; o[1] = (bf16)v0.y; o[2] = (bf16)v0.z; o[3] = (bf16)v0.w;
  o[4] = (bf16)v1.x; o[5] = (bf16)v1.y; o[6] = (bf16)v1.z; o[7] = (bf16)v1.w;
  *reinterpret_cast<bf16x8v*>(out + i) = o;
}

// =============== 256x256 BT-GEMM core, BK=64, 8 waves, 128KB LDS ==============
// COUNTED-VMCNT phase schedule (T3/T4). Per K-tile, 8 stage units of 64 rows:
//   U1:A0a U2:A1a U3:B0a U4:B0b U5:B1a U6:B1b U7:A0b U8:A1b
// Phases P1(a0xb0)/P2(a0xb1) read units 1-6 only; P3(a1xb1)/P4(a1xb0) add 7-8.
// Tile t's body issues units of tile t+1: P1->U1,U2  P2->U3,U4  P3->U5,U6
// P4->U7,U8. Invariants (per-thread vmcnt + barrier = collective):
//   boundary: outstanding <= {U7,U8 of this tile}          -> vmcnt(2)+barrier
//   mid-tile: outstanding <= {U1..U4 of next tile}         -> vmcnt(4)+barrier
// Loads never drain to 0; each unit gets ~2-3 phases of latency cover.
// __launch_bounds__ 2nd arg MUST stay 2 (R10: (512,4) spills acc -> 4.6x).
struct G256 {
  const char *pa, *pb;
  size_t lda2, ldb2;
  char* lds;
  int tid;
};

#define STG256(sd_, kt_, ldsOff_, rowOff_, isA_)                              \
  load_lds16(((isA_) ? g.pa : g.pb) + (size_t)(kt_) * 128 +                   \
                 (size_t)(rowOff_) * ((isA_) ? g.lda2 : g.ldb2),              \
             g.lds + (sd_) * 65536 + (ldsOff_) + g.tid * 16)

__device__ __forceinline__ void gemm256_core(const bf16* __restrict__ A,
                                             const bf16* __restrict__ B,
                                             int lda, int ldb, int brow, int bcol,
                                             int kt0, int ktn,
                                             f32x4 acc[2][2][4][2], char* lds) {
  const int tid = threadIdx.x;
  const int sr = tid >> 3;                              // staging row 0..63
  const int cs = ((tid & 7) << 4) ^ ((sr & 7) << 4);    // swizzled src byte col
  G256 g;
  g.lda2 = (size_t)lda * 2; g.ldb2 = (size_t)ldb * 2;
  g.pa = (const char*)A + (size_t)(brow + sr) * g.lda2 + cs;
  g.pb = (const char*)B + (size_t)(bcol + sr) * g.ldb2 + cs;
  g.lds = lds; g.tid = tid;

  const int lane = tid & 63, lrow = lane & 15, lkg = lane >> 4;
  const int wave = tid >> 6, wm = wave >> 2, wn = wave & 3;
  const int aReg = wm * 16384;                 // this wave's A half-tile
  const int bReg = 32768 + (wn >> 1) * 16384;  // this wave's B half-tile
  const int brow0 = (wn & 1) * 64;             // row base within B half
  const int swz = (lrow & 7) << 4;

  // prologue: stage tile kt0's 8 units in canonical order (no drain)
  STG256(0, kt0, 0,     0,   1);  // U1 A0a
  STG256(0, kt0, 16384, 128, 1);  // U2 A1a
  STG256(0, kt0, 32768, 0,   0);  // U3 B0a
  STG256(0, kt0, 40960, 64,  0);  // U4 B0b
  STG256(0, kt0, 49152, 128, 0);  // U5 B1a
  STG256(0, kt0, 57344, 192, 0);  // U6 B1b
  STG256(0, kt0, 8192,  64,  1);  // U7 A0b
  STG256(0, kt0, 24576, 192, 1);  // U8 A1b

  for (int t = 0; t < ktn; ++t) {
    const int d = t & 1, sd = d ^ 1;
    const char* db = lds + d * 65536;
    const int kn = kt0 + imin(t + 1, ktn - 1);  // clamped dup on last iter

    // ---- tile boundary: units 1-6 of this tile landed ----
    asm volatile("s_waitcnt vmcnt(2)" ::: "memory");
    __builtin_amdgcn_s_barrier();
    __builtin_amdgcn_sched_barrier(0);

    bf16x8v a0[4][2], a1[4][2], b0[2][2], b1[2][2];
    // P1: reads a0 + b0; issue U1,U2 of next tile; MFMA quadrant (mh0 x b0)
#pragma unroll
    for (int mt = 0; mt < 4; ++mt)
#pragma unroll
      for (int ks = 0; ks < 2; ++ks)
        a0[mt][ks] = *(const bf16x8v*)(db + aReg + (mt * 16 + lrow) * 128 + ((ks * 64 + lkg * 16) ^ swz));
#pragma unroll
    for (int nt = 0; nt < 2; ++nt)
#pragma unroll
      for (int ks = 0; ks < 2; ++ks)
        b0[nt][ks] = *(const bf16x8v*)(db + bReg + (brow0 + nt * 16 + lrow) * 128 + ((ks * 64 + lkg * 16) ^ swz));
    STG256(sd, kn, 0,     0,   1);
    STG256(sd, kn, 16384, 128, 1);
    __builtin_amdgcn_s_setprio(1);
#pragma unroll
    for (int mt = 0; mt < 4; ++mt)
#pragma unroll
      for (int nt = 0; nt < 2; ++nt)
#pragma unroll
        for (int ks = 0; ks < 2; ++ks)
          acc[0][0][mt][nt] = __builtin_amdgcn_mfma_f32_16x16x32_bf16(a0[mt][ks], b0[nt][ks], acc[0][0][mt][nt], 0, 0, 0);
    __builtin_amdgcn_s_setprio(0);

    // P2: reads b1; issue U3,U4; MFMA quadrant (mh0 x b1)
#pragma unroll
    for (int nt = 0; nt < 2; ++nt)
#pragma unroll
      for (int ks = 0; ks < 2; ++ks)
        b1[nt][ks] = *(const bf16x8v*)(db + bReg + (brow0 + 32 + nt * 16 + lrow) * 128 + ((ks * 64 + lkg * 16) ^ swz));
    STG256(sd, kn, 32768, 0,  0);
    STG256(sd, kn, 40960, 64, 0);
    __builtin_amdgcn_s_setprio(1);
#pragma unroll
    for (int mt = 0; mt < 4; ++mt)
#pragma unroll
      for (int nt = 0; nt < 2; ++nt)
#pragma unroll
        for (int ks = 0; ks < 2; ++ks)
          acc[0][1][mt][nt] = __builtin_amdgcn_mfma_f32_16x16x32_bf16(a0[mt][ks], b1[nt][ks], acc[0][1][mt][nt], 0, 0, 0);
    __builtin_amdgcn_s_setprio(0);

    // ---- mid-tile: units 7-8 of this tile landed ----
    asm volatile("s_waitcnt vmcnt(4)" ::: "memory");
    __builtin_amdgcn_s_barrier();
    __builtin_amdgcn_sched_barrier(0);

    // P3: reads a1; issue U5,U6; MFMA quadrant (mh1 x b1)
#pragma unroll
    for (int mt = 0; mt < 4; ++mt)
#pragma unroll
      for (int ks = 0; ks < 2; ++ks)
        a1[mt][ks] = *(const bf16x8v*)(db + aReg + ((64 + mt * 16 + lrow) * 128) + ((ks * 64 + lkg * 16) ^ swz));
    STG256(sd, kn, 49152, 128, 0);
    STG256(sd, kn, 57344, 192, 0);
    __builtin_amdgcn_s_setprio(1);
#pragma unroll
    for (int mt = 0; mt < 4; ++mt)
#pragma unroll
      for (int nt = 0; nt < 2; ++nt)
#pragma unroll
        for (int ks = 0; ks < 2; ++ks)
          acc[1][1][mt][nt] = __builtin_amdgcn_mfma_f32_16x16x32_bf16(a1[mt][ks], b1[nt][ks], acc[1][1][mt][nt], 0, 0, 0);
    __builtin_amdgcn_s_setprio(0);

    // P4: issue U7,U8; MFMA quadrant (mh1 x b0)
    STG256(sd, kn, 8192,  64,  1);
    STG256(sd, kn, 24576, 192, 1);
    __builtin_amdgcn_s_setprio(1);
#pragma unroll
    for (int mt = 0; mt < 4; ++mt)
#pragma unroll
      for (int nt = 0; nt < 2; ++nt)
#pragma unroll
        for (int ks = 0; ks < 2; ++ks)
          acc[1][0][mt][nt] = __builtin_amdgcn_mfma_f32_16x16x32_bf16(a1[mt][ks], b0[nt][ks], acc[1][0][mt][nt], 0, 0, 0);
    __builtin_amdgcn_s_setprio(0);
    __builtin_amdgcn_sched_barrier(0);
  }
}

// =============== 128x256 BT-GEMM core, BK=64, 8 waves, 3-dbuf 144KB LDS =======
// Depth-2 counted pipeline: every wave reads ALL 6 units at tile start, so the
// cover comes from a 3rd buffer: during tile t we stage tile t+2; boundary wait
// vmcnt(6) = tile t's 6 units landed, tile t+1's 6 still in flight.
struct G128 {
  const char *pa, *pb;
  size_t lda2, ldb2;
  char* lds;
  int tid;
};

__device__ __forceinline__ void stage_tile128(const G128& g, int sd, int kt) {
  const size_t kb = (size_t)kt * 128;
  char* d = g.lds + sd * 49152;
  const int to = g.tid * 16;
  load_lds16(g.pa + kb,                 d + 0     + to);  // A rows 0-63
  load_lds16(g.pa + kb + 64 * g.lda2,   d + 8192  + to);  // A rows 64-127
  load_lds16(g.pb + kb,                 d + 16384 + to);  // B rows 0-63
  load_lds16(g.pb + kb + 64  * g.ldb2,  d + 24576 + to);  // B rows 64-127
  load_lds16(g.pb + kb + 128 * g.ldb2,  d + 32768 + to);  // B rows 128-191
  load_lds16(g.pb + kb + 192 * g.ldb2,  d + 40960 + to);  // B rows 192-255
}

__device__ __forceinline__ void gemm128_core(const bf16* __restrict__ A,
                                             const bf16* __restrict__ B,
                                             int lda, int ldb, int brow, int bcol,
                                             int kt0, int ktn,
                                             f32x4 acc[2][4][2], char* lds) {
  const int tid = threadIdx.x;
  const int sr = tid >> 3;
  const int cs = ((tid & 7) << 4) ^ ((sr & 7) << 4);
  G128 g;
  g.lda2 = (size_t)lda * 2; g.ldb2 = (size_t)ldb * 2;
  g.pa = (const char*)A + (size_t)(brow + sr) * g.lda2 + cs;
  g.pb = (const char*)B + (size_t)(bcol + sr) * g.ldb2 + cs;
  g.lds = lds; g.tid = tid;

  const int lane = tid & 63, lrow = lane & 15, lkg = lane >> 4;
  const int wave = tid >> 6, wm = wave >> 2, wn = wave & 3;
  const int swz = (lrow & 7) << 4;

  stage_tile128(g, 0, kt0);
  stage_tile128(g, 1, kt0 + imin(1, ktn - 1));

  int d = 0;
  for (int t = 0; t < ktn; ++t) {
    // boundary: tile t's 6 units landed; tile t+1's 6 may be outstanding
    asm volatile("s_waitcnt vmcnt(6)" ::: "memory");
    __builtin_amdgcn_s_barrier();
    __builtin_amdgcn_sched_barrier(0);

    int sd = d + 2; if (sd >= 3) sd -= 3;
    stage_tile128(g, sd, kt0 + imin(t + 2, ktn - 1));  // clamped dup near tail
    const char* db = lds + d * 49152;

    bf16x8v a[4][2], b0[2][2], b1[2][2];
#pragma unroll
    for (int nt = 0; nt < 2; ++nt)
#pragma unroll
      for (int ks = 0; ks < 2; ++ks) {
        const int ck = (ks * 64 + lkg * 16) ^ swz;
        b0[nt][ks] = *(const bf16x8v*)(db + 16384 + (wn * 64 + nt * 16 + lrow) * 128 + ck);
        b1[nt][ks] = *(const bf16x8v*)(db + 16384 + (wn * 64 + 32 + nt * 16 + lrow) * 128 + ck);
      }
#pragma unroll
    for (int mt = 0; mt < 4; ++mt)
#pragma unroll
      for (int ks = 0; ks < 2; ++ks)
        a[mt][ks] = *(const bf16x8v*)(db + (wm * 64 + mt * 16 + lrow) * 128 + ((ks * 64 + lkg * 16) ^ swz));
    __builtin_amdgcn_s_setprio(1);
#pragma unroll
    for (int mt = 0; mt < 4; ++mt)
#pragma unroll
      for (int nt = 0; nt < 2; ++nt)
#pragma unroll
        for (int ks = 0; ks < 2; ++ks) {
          acc[0][mt][nt] = __builtin_amdgcn_mfma_f32_16x16x32_bf16(a[mt][ks], b0[nt][ks], acc[0][mt][nt], 0, 0, 0);
          acc[1][mt][nt] = __builtin_amdgcn_mfma_f32_16x16x32_bf16(a[mt][ks], b1[nt][ks], acc[1][mt][nt], 0, 0, 0);
        }
    __builtin_amdgcn_s_setprio(0);
    __builtin_amdgcn_sched_barrier(0);
    if (++d == 3) d = 0;
  }
}

#define ACC256_INIT()                         \
  f32x4 acc[2][2][4][2];                      \
  {                                           \
    f32x4 z = {0.f, 0.f, 0.f, 0.f};           \
    for (int a1 = 0; a1 < 2; ++a1)            \
      for (int a2 = 0; a2 < 2; ++a2)          \
        for (int a3 = 0; a3 < 4; ++a3)        \
          for (int a4 = 0; a4 < 2; ++a4) acc[a1][a2][a3][a4] = z; \
  }

#define EPI_BASES()                                             \
  const int lane = threadIdx.x & 63;                            \
  const int wave = threadIdx.x >> 6;                            \
  const int wm = wave >> 2, wn = wave & 3;                      \
  const int rb = wm * 128 + ((lane >> 4) << 2);                 \
  const int cb = wn * 64 + (lane & 15);

// ---------------- QK projection, 128x256 tiles, full-chip grid ----------------
// grid 256 = 2z x 32bi x 4bj (bj inner), XCD-swizzled. K-tiles: 16.
__global__ __launch_bounds__(512, 2) void qk_kernel(const bf16* __restrict__ xb,
                                                    const bf16* __restrict__ Wq,
                                                    const bf16* __restrict__ Wk,
                                                    bf16* __restrict__ Q,
                                                    bf16* __restrict__ K) {
  extern __shared__ char lds[];
  const int l = xcd_swz(blockIdx.x, 256);
  const int z = l >> 7, tt = l & 127, bi = tt >> 2, bj = tt & 3;
  const bf16* W = (z == 0) ? Wq : Wk;
  f32x4 acc[2][4][2];
  {
    f32x4 zr = {0.f, 0.f, 0.f, 0.f};
    for (int a1 = 0; a1 < 2; ++a1)
      for (int a2 = 0; a2 < 4; ++a2)
        for (int a3 = 0; a3 < 2; ++a3) acc[a1][a2][a3] = zr;
  }
  gemm128_core(xb, W, DIN, DIN, bi * 128, bj * 256, 0, 16, acc, lds);
  const int lane = threadIdx.x & 63;
  const int wave = threadIdx.x >> 6;
  const int wm = wave >> 2, wn = wave & 3;
  const int rbase = bi * 128 + wm * 64 + ((lane >> 4) << 2);
  const int cbase = bj * 256 + wn * 64 + (lane & 15);
  bf16* O = (z == 0) ? Q : K;
#pragma unroll
  for (int nh = 0; nh < 2; ++nh)
#pragma unroll
    for (int mt = 0; mt < 4; ++mt)
#pragma unroll
      for (int nt = 0; nt < 2; ++nt)
#pragma unroll
        for (int j = 0; j < 4; ++j)
          O[(size_t)(rbase + mt * 16 + j) * DOUT + (cbase + nh * 32 + nt * 16)] =
              (bf16)acc[nh][mt][nt][j];
}

// ---------------- scores (136 tri blocks, bf16 out) + V-projection (64) -------
// grid 200, XCD-swizzled. Both classes co-resident: V-proj overlaps scores.
__global__ __launch_bounds__(512, 2) void scores_v_kernel(const bf16* __restrict__ Q,
                                                          const bf16* __restrict__ Km,
                                                          bf16* __restrict__ Scb,
                                                          const bf16* __restrict__ xb,
                                                          const bf16* __restrict__ Wv,
                                                          bf16* __restrict__ Vt) {
  extern __shared__ char lds[];
  const int l = xcd_swz(blockIdx.x, 200);
  if (l < 64) {
    // ---- V projection: out written transposed into Vt [1024][4096] ----
    const int bi = l >> 2, bj = l & 3;
    ACC256_INIT();
    gemm256_core(xb, Wv, DIN, DIN, bi * 256, bj * 256, 0, 16, acc, lds);
    EPI_BASES();
    const int rbase = bi * 256 + rb, cbase = bj * 256 + cb;
#pragma unroll
    for (int mh = 0; mh < 2; ++mh)
#pragma unroll
      for (int nh = 0; nh < 2; ++nh)
#pragma unroll
        for (int mt = 0; mt < 4; ++mt)
#pragma unroll
          for (int nt = 0; nt < 2; ++nt)
#pragma unroll
            for (int j = 0; j < 4; ++j)
              Vt[(size_t)(cbase + nh * 32 + nt * 16) * SEQ + (rbase + mh * 64 + mt * 16 + j)] =
                  (bf16)acc[mh][nh][mt][nt][j];
  } else {
    // ---- scores tile (triangular), written bf16 ----
    const int t = l - 64;
    int bi = (int)((sqrtf(8.0f * (float)t + 1.0f) - 1.0f) * 0.5f);
    while ((bi + 1) * (bi + 2) / 2 <= t) ++bi;
    while (bi * (bi + 1) / 2 > t) --bi;
    const int bj = t - bi * (bi + 1) / 2;
    ACC256_INIT();
    gemm256_core(Q, Km, DOUT, DOUT, bi * 256, bj * 256, 0, 16, acc, lds);
    EPI_BASES();
    const int rbase = bi * 256 + rb, cbase = bj * 256 + cb;
    const float scale = 0.03125f;  // 1/sqrt(1024)
#pragma unroll
    for (int mh = 0; mh < 2; ++mh)
#pragma unroll
      for (int nh = 0; nh < 2; ++nh)
#pragma unroll
        for (int mt = 0; mt < 4; ++mt)
#pragma unroll
          for (int nt = 0; nt < 2; ++nt)
#pragma unroll
            for (int j = 0; j < 4; ++j)
              Scb[(size_t)(rbase + mh * 64 + mt * 16 + j) * SEQ + (cbase + nh * 32 + nt * 16)] =
                  (bf16)(acc[mh][nh][mt][nt][j] * scale);
  }
}

// ---------------- row softmax: one WAVE per row, barrier-free -----------------
// grid 1024 x 256 thr = 4 waves/block, wave wid owns row 4095-(bid*4+wid).
// Row staged in the wave's private 16KB LDS quadrant; 64-lane shfl_xor
// butterfly leaves max/sum in every lane -> no __syncthreads anywhere.
__global__ __launch_bounds__(256) void softmax_kernel(const bf16* __restrict__ Scb,
                                                      bf16* __restrict__ P) {
  __shared__ float rowbuf[4][SEQ];
  const int wid = threadIdx.x >> 6, lane = threadIdx.x & 63;
  const int r = (SEQ - 1) - (blockIdx.x * 4 + wid);  // longest rows first
  const int n = r + 1;
  const int nw8 = ((r >> 8) + 1) << 5;  // padded row length / 8 (256-col blocks)
  const bf16* src = Scb + (size_t)r * SEQ;
  float* buf = rowbuf[wid];
  const float NEG = -__builtin_inff();

  float lmax = NEG;
  for (int g = lane; g < nw8; g += 64) {
    bf16x8v v = *reinterpret_cast<const bf16x8v*>(src + g * 8);
    const int b = g * 8;
    float f[8];
#pragma unroll
    for (int j = 0; j < 8; ++j) {
      f[j] = (b + j < n) ? (float)v[j] : NEG;
      lmax = fmaxf(lmax, f[j]);
    }
    reinterpret_cast<float4*>(buf)[g * 2]     = make_float4(f[0], f[1], f[2], f[3]);
    reinterpret_cast<float4*>(buf)[g * 2 + 1] = make_float4(f[4], f[5], f[6], f[7]);
  }
#pragma unroll
  for (int m = 32; m >= 1; m >>= 1) lmax = fmaxf(lmax, __shfl_xor(lmax, m, 64));
  const float rmax = lmax;  // butterfly: every lane holds the row max

  const int nw4 = nw8 * 2;
  float lsum = 0.f;
  for (int g = lane; g < nw4; g += 64) {
    float4 v = reinterpret_cast<const float4*>(buf)[g];
    v.x = __expf(v.x - rmax);
    v.y = __expf(v.y - rmax);
    v.z = __expf(v.z - rmax);
    v.w = __expf(v.w - rmax);
    reinterpret_cast<float4*>(buf)[g] = v;
    lsum += v.x + v.y + v.z + v.w;
  }
#pragma unroll
  for (int m = 32; m >= 1; m >>= 1) lsum += __shfl_xor(lsum, m, 64);
  const float inv = 1.0f / lsum;

  bf16* dst = P + (size_t)r * SEQ;
  for (int g = lane; g < nw4; g += 64) {
    float4 v = reinterpret_cast<const float4*>(buf)[g];
    bf16x4v o;
    o[0] = (bf16)(v.x * inv);
    o[1] = (bf16)(v.y * inv);
    o[2] = (bf16)(v.z * inv);
    o[3] = (bf16)(v.w * inv);
    *reinterpret_cast<bf16x4v*>(dst + g * 4) = o;
  }
}

// ---------------- out = P @ V, split-K, ALL chunks -> bf16 partials -----------
// grid 244 = 61 chunk-slots x 4 bj, XCD-swizzled. nch(bi)=ceil((bi+1)*4/10),
// <=10 K-tiles per chunk. Every chunk stores a bf16 partial tile (244 slots x
// 128KB = 30.5MB in the freed Sc region). reduce_kernel sums all partials and
// writes Out exactly once (no RMW, covers every element).
__device__ __constant__ int kNch[16]  = {1, 1, 2, 2, 2, 3, 3, 4, 4, 4, 5, 5, 6, 6, 6, 7};
__device__ __constant__ int kPref[16] = {0, 1, 2, 4, 6, 8, 11, 14, 18, 22, 26, 31, 36, 42, 48, 54};

__global__ __launch_bounds__(512, 2) void pv_kernel(const bf16* __restrict__ P,
                                                    const bf16* __restrict__ Vt,
                                                    bf16* __restrict__ Par) {
  extern __shared__ char lds[];
  const int l = xcd_swz(blockIdx.x, 244);
  const int bj = l & 3;
  int c = l >> 2, bi = 0;
  for (;;) {
    const int nch = kNch[bi];
    if (c < nch) break;
    c -= nch; ++bi;
  }
  const int nch = kNch[bi];
  const int Ti = (bi + 1) * 4;
  const int base = Ti / nch, rem = Ti % nch;
  const int kt0 = c * base + imin(c, rem);
  const int ktn = base + (c < rem ? 1 : 0);
  ACC256_INIT();
  gemm256_core(P, Vt, SEQ, SEQ, bi * 256, bj * 256, kt0, ktn, acc, lds);
  EPI_BASES();
  // bf16 partial tile, row-major 256x256
  const int slot = (kPref[bi] + c) * 4 + bj;
  bf16* Pp = Par + (size_t)slot * 65536;
#pragma unroll
  for (int mh = 0; mh < 2; ++mh)
#pragma unroll
    for (int nh = 0; nh < 2; ++nh)
#pragma unroll
      for (int mt = 0; mt < 4; ++mt)
#pragma unroll
        for (int nt = 0; nt < 2; ++nt)
#pragma unroll
          for (int j = 0; j < 4; ++j)
            Pp[(rb + mh * 64 + mt * 16 + j) * 256 + (cb + nh * 32 + nt * 16)] =
                (bf16)acc[mh][nh][mt][nt][j];
}

// ---------------- reduction: Out[tile] = sum of its bf16 partials -------------
// grid 64 tiles x 32 sub-blocks = 2048, 256 thr, 8 elems/thread. Pure write
// (no RMW) -- covers all of Out.
__global__ __launch_bounds__(256) void reduce_kernel(const bf16* __restrict__ Par,
                                                     float* __restrict__ Out) {
  const int blk = blockIdx.x;
  const int t2 = blk >> 5, sub = blk & 31;
  const int bi = t2 >> 2, bj = t2 & 3;
  const int npart = kNch[bi];                 // 1..7
  const int pb = kPref[bi] * 4 + bj;          // partial c at slot pb + c*4
  const int elem = sub * 2048 + threadIdx.x * 8;
  const int r = elem >> 8, cc = elem & 255;
  float s[8] = {0.f, 0.f, 0.f, 0.f, 0.f, 0.f, 0.f, 0.f};
  for (int p = 0; p < npart; ++p) {
    const bf16x8v v = *reinterpret_cast<const bf16x8v*>(Par + (size_t)(pb + p * 4) * 65536 + elem);
#pragma unroll
    for (int j = 0; j < 8; ++j) s[j] += (float)v[j];
  }
  float* op = Out + (size_t)(bi * 256 + r) * DOUT + bj * 256 + cc;
  *reinterpret_cast<float4*>(op)     = make_float4(s[0], s[1], s[2], s[3]);
  *reinterpret_cast<float4*>(op + 4) = make_float4(s[4], s[5], s[6], s[7]);
}

extern "C" void kernel_launch(void* const* d_in, const int* in_sizes, int n_in,
                              void* d_out, int out_size, void* d_ws, size_t ws_size,
                              hipStream_t stream) {
  const float* x  = (const float*)d_in[0];
  const float* Wq = (const float*)d_in[1];
  const float* Wk = (const float*)d_in[2];
  const float* Wv = (const float*)d_in[3];
  float* Out = (float*)d_out;

  char* base = (char*)d_ws;
  bf16* xb   = (bf16*)(base + 0);          //  8 MB [4096x1024]
  bf16* wqb  = (bf16*)(base + 8388608);    //  2 MB
  bf16* wkb  = (bf16*)(base + 10485760);   //  2 MB
  bf16* wvb  = (bf16*)(base + 12582912);   //  2 MB
  bf16* Qb   = (bf16*)(base + 14680064);   //  8 MB
  bf16* Kb   = (bf16*)(base + 23068672);   //  8 MB
  bf16* Vtb  = (bf16*)(base + 31457280);   //  8 MB [1024x4096] transposed
  bf16* Scb  = (bf16*)(base + 39845888);   // 32 MB [4096x4096] bf16 scores
  bf16* Par  = (bf16*)(base + 73400320);   // 30.5 MB: pv bf16 partials (244 slots)
  bf16* P    = (bf16*)(base + 106954752);  // 32 MB [4096x4096] bf16
  // total ws use unchanged: 140,509,184 bytes

  (void)hipFuncSetAttribute((const void*)qk_kernel,
                            hipFuncAttributeMaxDynamicSharedMemorySize, 147456);
  (void)hipFuncSetAttribute((const void*)scores_v_kernel,
                            hipFuncAttributeMaxDynamicSharedMemorySize, 131072);
  (void)hipFuncSetAttribute((const void*)pv_kernel,
                            hipFuncAttributeMaxDynamicSharedMemorySize, 131072);

  cast_all_kernel<<<3584, 256, 0, stream>>>(x, Wq, Wk, Wv, xb, wqb, wkb, wvb);

  qk_kernel<<<256, 512, 147456, stream>>>(xb, wqb, wkb, Qb, Kb);
  scores_v_kernel<<<200, 512, 131072, stream>>>(Qb, Kb, Scb, xb, wvb, Vtb);
  softmax_kernel<<<SEQ / 4, 256, 0, stream>>>(Scb, P);
  pv_kernel<<<244, 512, 131072, stream>>>(P, Vtb, Par);
  reduce_kernel<<<2048, 256, 0, stream>>>(Par, Out);
}

// Round 18
// 105.223 us; speedup vs baseline: 1.0071x; 1.0071x over previous
//
#include <hip/hip_runtime.h>
#include <hip/hip_bf16.h>
#include <stdint.h>

#define SEQ 4096
#define DIN 1024
#define DOUT 1024

typedef __bf16 bf16;
typedef __bf16 bf16x4v __attribute__((ext_vector_type(4)));
typedef __bf16 bf16x8v __attribute__((ext_vector_type(8)));
typedef float f32x4 __attribute__((ext_vector_type(4)));

#define AS1 __attribute__((address_space(1)))
#define AS3 __attribute__((address_space(3)))

__device__ __forceinline__ void load_lds16(const void* g, void* l) {
  __builtin_amdgcn_global_load_lds((const AS1 uint32_t*)g, (AS3 uint32_t*)l, 16, 0, 0);
}

__device__ __forceinline__ int imin(int a, int b) { return a < b ? a : b; }

// m204 bijective XCD swizzle
__device__ __forceinline__ int xcd_swz(int orig, int nwg) {
  const int q = nwg >> 3, r = nwg & 7;
  const int x = orig & 7, idx = orig >> 3;
  return (x < r ? x * (q + 1) : r * (q + 1) + (x - r) * q) + idx;
}

// ---------------- fused cast fp32 -> bf16, 8 elems/thread (exact 1D grid) -----
// x: 2048 blocks; Wq/Wk/Wv: 512 each -> grid 3584.
__global__ __launch_bounds__(256) void cast_all_kernel(
    const float* __restrict__ x, const float* __restrict__ wq,
    const float* __restrict__ wk, const float* __restrict__ wv,
    bf16* __restrict__ xb, bf16* __restrict__ wqb,
    bf16* __restrict__ wkb, bf16* __restrict__ wvb) {
  const int id = blockIdx.x;
  const float* in; bf16* out; int blk;
  if (id < 2048) {
    in = x; out = xb; blk = id;
  } else {
    const int w = (id - 2048) >> 9;
    blk = (id - 2048) & 511;
    in = (w == 0) ? wq : (w == 1) ? wk : wv;
    out = (w == 0) ? wqb : (w == 1) ? wkb : wvb;
  }
  const int i = (blk * 256 + threadIdx.x) * 8;
  float4 v0 = *reinterpret_cast<const float4*>(in + i);
  float4 v1 = *reinterpret_cast<const float4*>(in + i + 4);
  bf16x8v o;
  o[0] = (bf16)v0.x; o[1] = (bf16)v0.y; o[2] = (bf16)v0.z; o[3] = (bf16)v0.w;
  o[4] = (bf16)v1.x; o[5] = (bf16)v1.y; o[6] = (bf16)v1.z; o[7] = (bf16)v1.w;
  *reinterpret_cast<bf16x8v*>(out + i) = o;
}

// =============== 256x256 BT-GEMM core, BK=64, 8 waves, 128KB LDS ==============
// COUNTED-VMCNT phase schedule (T3/T4). Per K-tile, 8 stage units of 64 rows:
//   U1:A0a U2:A1a U3:B0a U4:B0b U5:B1a U6:B1b U7:A0b U8:A1b
// Phases P1(a0xb0)/P2(a0xb1) read units 1-6 only; P3(a1xb1)/P4(a1xb0) add 7-8.
// Tile t's body issues units of tile t+1: P1->U1,U2  P2->U3,U4  P3->U5,U6
// P4->U7,U8. Invariants (per-thread vmcnt + barrier = collective):
//   boundary: outstanding <= {U7,U8 of this tile}          -> vmcnt(2)+barrier
//   mid-tile: outstanding <= {U1..U4 of next tile}         -> vmcnt(4)+barrier
// Loads never drain to 0; each unit gets ~2-3 phases of latency cover.
// __launch_bounds__ 2nd arg MUST stay 2 (R10: (512,4) spills acc -> 4.6x).
struct G256 {
  const char *pa, *pb;
  size_t lda2, ldb2;
  char* lds;
  int tid;
};

#define STG256(sd_, kt_, ldsOff_, rowOff_, isA_)                              \
  load_lds16(((isA_) ? g.pa : g.pb) + (size_t)(kt_) * 128 +                   \
                 (size_t)(rowOff_) * ((isA_) ? g.lda2 : g.ldb2),              \
             g.lds + (sd_) * 65536 + (ldsOff_) + g.tid * 16)

__device__ __forceinline__ void gemm256_core(const bf16* __restrict__ A,
                                             const bf16* __restrict__ B,
                                             int lda, int ldb, int brow, int bcol,
                                             int kt0, int ktn,
                                             f32x4 acc[2][2][4][2], char* lds) {
  const int tid = threadIdx.x;
  const int sr = tid >> 3;                              // staging row 0..63
  const int cs = ((tid & 7) << 4) ^ ((sr & 7) << 4);    // swizzled src byte col
  G256 g;
  g.lda2 = (size_t)lda * 2; g.ldb2 = (size_t)ldb * 2;
  g.pa = (const char*)A + (size_t)(brow + sr) * g.lda2 + cs;
  g.pb = (const char*)B + (size_t)(bcol + sr) * g.ldb2 + cs;
  g.lds = lds; g.tid = tid;

  const int lane = tid & 63, lrow = lane & 15, lkg = lane >> 4;
  const int wave = tid >> 6, wm = wave >> 2, wn = wave & 3;
  const int aReg = wm * 16384;                 // this wave's A half-tile
  const int bReg = 32768 + (wn >> 1) * 16384;  // this wave's B half-tile
  const int brow0 = (wn & 1) * 64;             // row base within B half
  const int swz = (lrow & 7) << 4;

  // prologue: stage tile kt0's 8 units in canonical order (no drain)
  STG256(0, kt0, 0,     0,   1);  // U1 A0a
  STG256(0, kt0, 16384, 128, 1);  // U2 A1a
  STG256(0, kt0, 32768, 0,   0);  // U3 B0a
  STG256(0, kt0, 40960, 64,  0);  // U4 B0b
  STG256(0, kt0, 49152, 128, 0);  // U5 B1a
  STG256(0, kt0, 57344, 192, 0);  // U6 B1b
  STG256(0, kt0, 8192,  64,  1);  // U7 A0b
  STG256(0, kt0, 24576, 192, 1);  // U8 A1b

  for (int t = 0; t < ktn; ++t) {
    const int d = t & 1, sd = d ^ 1;
    const char* db = lds + d * 65536;
    const int kn = kt0 + imin(t + 1, ktn - 1);  // clamped dup on last iter

    // ---- tile boundary: units 1-6 of this tile landed ----
    asm volatile("s_waitcnt vmcnt(2)" ::: "memory");
    __builtin_amdgcn_s_barrier();
    __builtin_amdgcn_sched_barrier(0);

    bf16x8v a0[4][2], a1[4][2], b0[2][2], b1[2][2];
    // P1: reads a0 + b0; issue U1,U2 of next tile; MFMA quadrant (mh0 x b0)
#pragma unroll
    for (int mt = 0; mt < 4; ++mt)
#pragma unroll
      for (int ks = 0; ks < 2; ++ks)
        a0[mt][ks] = *(const bf16x8v*)(db + aReg + (mt * 16 + lrow) * 128 + ((ks * 64 + lkg * 16) ^ swz));
#pragma unroll
    for (int nt = 0; nt < 2; ++nt)
#pragma unroll
      for (int ks = 0; ks < 2; ++ks)
        b0[nt][ks] = *(const bf16x8v*)(db + bReg + (brow0 + nt * 16 + lrow) * 128 + ((ks * 64 + lkg * 16) ^ swz));
    STG256(sd, kn, 0,     0,   1);
    STG256(sd, kn, 16384, 128, 1);
    __builtin_amdgcn_s_setprio(1);
#pragma unroll
    for (int mt = 0; mt < 4; ++mt)
#pragma unroll
      for (int nt = 0; nt < 2; ++nt)
#pragma unroll
        for (int ks = 0; ks < 2; ++ks)
          acc[0][0][mt][nt] = __builtin_amdgcn_mfma_f32_16x16x32_bf16(a0[mt][ks], b0[nt][ks], acc[0][0][mt][nt], 0, 0, 0);
    __builtin_amdgcn_s_setprio(0);

    // P2: reads b1; issue U3,U4; MFMA quadrant (mh0 x b1)
#pragma unroll
    for (int nt = 0; nt < 2; ++nt)
#pragma unroll
      for (int ks = 0; ks < 2; ++ks)
        b1[nt][ks] = *(const bf16x8v*)(db + bReg + (brow0 + 32 + nt * 16 + lrow) * 128 + ((ks * 64 + lkg * 16) ^ swz));
    STG256(sd, kn, 32768, 0,  0);
    STG256(sd, kn, 40960, 64, 0);
    __builtin_amdgcn_s_setprio(1);
#pragma unroll
    for (int mt = 0; mt < 4; ++mt)
#pragma unroll
      for (int nt = 0; nt < 2; ++nt)
#pragma unroll
        for (int ks = 0; ks < 2; ++ks)
          acc[0][1][mt][nt] = __builtin_amdgcn_mfma_f32_16x16x32_bf16(a0[mt][ks], b1[nt][ks], acc[0][1][mt][nt], 0, 0, 0);
    __builtin_amdgcn_s_setprio(0);

    // ---- mid-tile: units 7-8 of this tile landed ----
    asm volatile("s_waitcnt vmcnt(4)" ::: "memory");
    __builtin_amdgcn_s_barrier();
    __builtin_amdgcn_sched_barrier(0);

    // P3: reads a1; issue U5,U6; MFMA quadrant (mh1 x b1)
#pragma unroll
    for (int mt = 0; mt < 4; ++mt)
#pragma unroll
      for (int ks = 0; ks < 2; ++ks)
        a1[mt][ks] = *(const bf16x8v*)(db + aReg + ((64 + mt * 16 + lrow) * 128) + ((ks * 64 + lkg * 16) ^ swz));
    STG256(sd, kn, 49152, 128, 0);
    STG256(sd, kn, 57344, 192, 0);
    __builtin_amdgcn_s_setprio(1);
#pragma unroll
    for (int mt = 0; mt < 4; ++mt)
#pragma unroll
      for (int nt = 0; nt < 2; ++nt)
#pragma unroll
        for (int ks = 0; ks < 2; ++ks)
          acc[1][1][mt][nt] = __builtin_amdgcn_mfma_f32_16x16x32_bf16(a1[mt][ks], b1[nt][ks], acc[1][1][mt][nt], 0, 0, 0);
    __builtin_amdgcn_s_setprio(0);

    // P4: issue U7,U8; MFMA quadrant (mh1 x b0)
    STG256(sd, kn, 8192,  64,  1);
    STG256(sd, kn, 24576, 192, 1);
    __builtin_amdgcn_s_setprio(1);
#pragma unroll
    for (int mt = 0; mt < 4; ++mt)
#pragma unroll
      for (int nt = 0; nt < 2; ++nt)
#pragma unroll
        for (int ks = 0; ks < 2; ++ks)
          acc[1][0][mt][nt] = __builtin_amdgcn_mfma_f32_16x16x32_bf16(a1[mt][ks], b0[nt][ks], acc[1][0][mt][nt], 0, 0, 0);
    __builtin_amdgcn_s_setprio(0);
    __builtin_amdgcn_sched_barrier(0);
  }
}

// =============== 128x256 BT-GEMM core, BK=64, 8 waves, 3-dbuf 144KB LDS =======
// Depth-2 counted pipeline: every wave reads ALL 6 units at tile start, so the
// cover comes from a 3rd buffer: during tile t we stage tile t+2; boundary wait
// vmcnt(6) = tile t's 6 units landed, tile t+1's 6 still in flight.
struct G128 {
  const char *pa, *pb;
  size_t lda2, ldb2;
  char* lds;
  int tid;
};

__device__ __forceinline__ void stage_tile128(const G128& g, int sd, int kt) {
  const size_t kb = (size_t)kt * 128;
  char* d = g.lds + sd * 49152;
  const int to = g.tid * 16;
  load_lds16(g.pa + kb,                 d + 0     + to);  // A rows 0-63
  load_lds16(g.pa + kb + 64 * g.lda2,   d + 8192  + to);  // A rows 64-127
  load_lds16(g.pb + kb,                 d + 16384 + to);  // B rows 0-63
  load_lds16(g.pb + kb + 64  * g.ldb2,  d + 24576 + to);  // B rows 64-127
  load_lds16(g.pb + kb + 128 * g.ldb2,  d + 32768 + to);  // B rows 128-191
  load_lds16(g.pb + kb + 192 * g.ldb2,  d + 40960 + to);  // B rows 192-255
}

__device__ __forceinline__ void gemm128_core(const bf16* __restrict__ A,
                                             const bf16* __restrict__ B,
                                             int lda, int ldb, int brow, int bcol,
                                             int kt0, int ktn,
                                             f32x4 acc[2][4][2], char* lds) {
  const int tid = threadIdx.x;
  const int sr = tid >> 3;
  const int cs = ((tid & 7) << 4) ^ ((sr & 7) << 4);
  G128 g;
  g.lda2 = (size_t)lda * 2; g.ldb2 = (size_t)ldb * 2;
  g.pa = (const char*)A + (size_t)(brow + sr) * g.lda2 + cs;
  g.pb = (const char*)B + (size_t)(bcol + sr) * g.ldb2 + cs;
  g.lds = lds; g.tid = tid;

  const int lane = tid & 63, lrow = lane & 15, lkg = lane >> 4;
  const int wave = tid >> 6, wm = wave >> 2, wn = wave & 3;
  const int swz = (lrow & 7) << 4;

  stage_tile128(g, 0, kt0);
  stage_tile128(g, 1, kt0 + imin(1, ktn - 1));

  int d = 0;
  for (int t = 0; t < ktn; ++t) {
    // boundary: tile t's 6 units landed; tile t+1's 6 may be outstanding
    asm volatile("s_waitcnt vmcnt(6)" ::: "memory");
    __builtin_amdgcn_s_barrier();
    __builtin_amdgcn_sched_barrier(0);

    int sd = d + 2; if (sd >= 3) sd -= 3;
    stage_tile128(g, sd, kt0 + imin(t + 2, ktn - 1));  // clamped dup near tail
    const char* db = lds + d * 49152;

    bf16x8v a[4][2], b0[2][2], b1[2][2];
#pragma unroll
    for (int nt = 0; nt < 2; ++nt)
#pragma unroll
      for (int ks = 0; ks < 2; ++ks) {
        const int ck = (ks * 64 + lkg * 16) ^ swz;
        b0[nt][ks] = *(const bf16x8v*)(db + 16384 + (wn * 64 + nt * 16 + lrow) * 128 + ck);
        b1[nt][ks] = *(const bf16x8v*)(db + 16384 + (wn * 64 + 32 + nt * 16 + lrow) * 128 + ck);
      }
#pragma unroll
    for (int mt = 0; mt < 4; ++mt)
#pragma unroll
      for (int ks = 0; ks < 2; ++ks)
        a[mt][ks] = *(const bf16x8v*)(db + (wm * 64 + mt * 16 + lrow) * 128 + ((ks * 64 + lkg * 16) ^ swz));
    __builtin_amdgcn_s_setprio(1);
#pragma unroll
    for (int mt = 0; mt < 4; ++mt)
#pragma unroll
      for (int nt = 0; nt < 2; ++nt)
#pragma unroll
        for (int ks = 0; ks < 2; ++ks) {
          acc[0][mt][nt] = __builtin_amdgcn_mfma_f32_16x16x32_bf16(a[mt][ks], b0[nt][ks], acc[0][mt][nt], 0, 0, 0);
          acc[1][mt][nt] = __builtin_amdgcn_mfma_f32_16x16x32_bf16(a[mt][ks], b1[nt][ks], acc[1][mt][nt], 0, 0, 0);
        }
    __builtin_amdgcn_s_setprio(0);
    __builtin_amdgcn_sched_barrier(0);
    if (++d == 3) d = 0;
  }
}

#define ACC256_INIT()                         \
  f32x4 acc[2][2][4][2];                      \
  {                                           \
    f32x4 z = {0.f, 0.f, 0.f, 0.f};           \
    for (int a1 = 0; a1 < 2; ++a1)            \
      for (int a2 = 0; a2 < 2; ++a2)          \
        for (int a3 = 0; a3 < 4; ++a3)        \
          for (int a4 = 0; a4 < 2; ++a4) acc[a1][a2][a3][a4] = z; \
  }

#define EPI_BASES()                                             \
  const int lane = threadIdx.x & 63;                            \
  const int wave = threadIdx.x >> 6;                            \
  const int wm = wave >> 2, wn = wave & 3;                      \
  const int rb = wm * 128 + ((lane >> 4) << 2);                 \
  const int cb = wn * 64 + (lane & 15);

// ---------------- QK projection, 128x256 tiles, full-chip grid ----------------
// grid 256 = 2z x 32bi x 4bj (bj inner), XCD-swizzled. K-tiles: 16.
__global__ __launch_bounds__(512, 2) void qk_kernel(const bf16* __restrict__ xb,
                                                    const bf16* __restrict__ Wq,
                                                    const bf16* __restrict__ Wk,
                                                    bf16* __restrict__ Q,
                                                    bf16* __restrict__ K) {
  extern __shared__ char lds[];
  const int l = xcd_swz(blockIdx.x, 256);
  const int z = l >> 7, tt = l & 127, bi = tt >> 2, bj = tt & 3;
  const bf16* W = (z == 0) ? Wq : Wk;
  f32x4 acc[2][4][2];
  {
    f32x4 zr = {0.f, 0.f, 0.f, 0.f};
    for (int a1 = 0; a1 < 2; ++a1)
      for (int a2 = 0; a2 < 4; ++a2)
        for (int a3 = 0; a3 < 2; ++a3) acc[a1][a2][a3] = zr;
  }
  gemm128_core(xb, W, DIN, DIN, bi * 128, bj * 256, 0, 16, acc, lds);
  const int lane = threadIdx.x & 63;
  const int wave = threadIdx.x >> 6;
  const int wm = wave >> 2, wn = wave & 3;
  const int rbase = bi * 128 + wm * 64 + ((lane >> 4) << 2);
  const int cbase = bj * 256 + wn * 64 + (lane & 15);
  bf16* O = (z == 0) ? Q : K;
#pragma unroll
  for (int nh = 0; nh < 2; ++nh)
#pragma unroll
    for (int mt = 0; mt < 4; ++mt)
#pragma unroll
      for (int nt = 0; nt < 2; ++nt)
#pragma unroll
        for (int j = 0; j < 4; ++j)
          O[(size_t)(rbase + mt * 16 + j) * DOUT + (cbase + nh * 32 + nt * 16)] =
              (bf16)acc[nh][mt][nt][j];
}

// ---------------- scores (136 tri blocks, bf16 out) + V-projection (64) -------
// grid 200, XCD-swizzled. Both classes co-resident: V-proj overlaps scores.
__global__ __launch_bounds__(512, 2) void scores_v_kernel(const bf16* __restrict__ Q,
                                                          const bf16* __restrict__ Km,
                                                          bf16* __restrict__ Scb,
                                                          const bf16* __restrict__ xb,
                                                          const bf16* __restrict__ Wv,
                                                          bf16* __restrict__ Vt) {
  extern __shared__ char lds[];
  const int l = xcd_swz(blockIdx.x, 200);
  if (l < 64) {
    // ---- V projection: out written transposed into Vt [1024][4096] ----
    const int bi = l >> 2, bj = l & 3;
    ACC256_INIT();
    gemm256_core(xb, Wv, DIN, DIN, bi * 256, bj * 256, 0, 16, acc, lds);
    EPI_BASES();
    const int rbase = bi * 256 + rb, cbase = bj * 256 + cb;
#pragma unroll
    for (int mh = 0; mh < 2; ++mh)
#pragma unroll
      for (int nh = 0; nh < 2; ++nh)
#pragma unroll
        for (int mt = 0; mt < 4; ++mt)
#pragma unroll
          for (int nt = 0; nt < 2; ++nt)
#pragma unroll
            for (int j = 0; j < 4; ++j)
              Vt[(size_t)(cbase + nh * 32 + nt * 16) * SEQ + (rbase + mh * 64 + mt * 16 + j)] =
                  (bf16)acc[mh][nh][mt][nt][j];
  } else {
    // ---- scores tile (triangular), written bf16 ----
    const int t = l - 64;
    int bi = (int)((sqrtf(8.0f * (float)t + 1.0f) - 1.0f) * 0.5f);
    while ((bi + 1) * (bi + 2) / 2 <= t) ++bi;
    while (bi * (bi + 1) / 2 > t) --bi;
    const int bj = t - bi * (bi + 1) / 2;
    ACC256_INIT();
    gemm256_core(Q, Km, DOUT, DOUT, bi * 256, bj * 256, 0, 16, acc, lds);
    EPI_BASES();
    const int rbase = bi * 256 + rb, cbase = bj * 256 + cb;
    const float scale = 0.03125f;  // 1/sqrt(1024)
#pragma unroll
    for (int mh = 0; mh < 2; ++mh)
#pragma unroll
      for (int nh = 0; nh < 2; ++nh)
#pragma unroll
        for (int mt = 0; mt < 4; ++mt)
#pragma unroll
          for (int nt = 0; nt < 2; ++nt)
#pragma unroll
            for (int j = 0; j < 4; ++j)
              Scb[(size_t)(rbase + mh * 64 + mt * 16 + j) * SEQ + (cbase + nh * 32 + nt * 16)] =
                  (bf16)(acc[mh][nh][mt][nt][j] * scale);
  }
}

// ---------------- row softmax: bf16 in, bf16 out, longest rows first ----------
__global__ __launch_bounds__(256) void softmax_kernel(const bf16* __restrict__ Scb,
                                                      bf16* __restrict__ P) {
  __shared__ float rowbuf[SEQ];
  __shared__ float red[8];
  const int r = (SEQ - 1) - blockIdx.x;  // longest rows dispatched first
  const int n = r + 1;
  const int nw8 = ((r >> 8) + 1) << 5;  // padded row length / 8 (256-col blocks)
  const int tid = threadIdx.x;
  const bf16* src = Scb + (size_t)r * SEQ;
  const float NEG = -__builtin_inff();

  float lmax = NEG;
  for (int g = tid; g < nw8; g += 256) {
    bf16x8v v = *reinterpret_cast<const bf16x8v*>(src + g * 8);
    const int b = g * 8;
    float f[8];
#pragma unroll
    for (int j = 0; j < 8; ++j) {
      f[j] = (b + j < n) ? (float)v[j] : NEG;
      lmax = fmaxf(lmax, f[j]);
    }
    reinterpret_cast<float4*>(rowbuf)[g * 2]     = make_float4(f[0], f[1], f[2], f[3]);
    reinterpret_cast<float4*>(rowbuf)[g * 2 + 1] = make_float4(f[4], f[5], f[6], f[7]);
  }
#pragma unroll
  for (int m = 32; m >= 1; m >>= 1) lmax = fmaxf(lmax, __shfl_xor(lmax, m, 64));
  if ((tid & 63) == 0) red[tid >> 6] = lmax;
  __syncthreads();
  const float rmax = fmaxf(fmaxf(red[0], red[1]), fmaxf(red[2], red[3]));

  const int nw4 = nw8 * 2;
  float lsum = 0.f;
  for (int g = tid; g < nw4; g += 256) {
    float4 v = reinterpret_cast<const float4*>(rowbuf)[g];
    v.x = __expf(v.x - rmax);
    v.y = __expf(v.y - rmax);
    v.z = __expf(v.z - rmax);
    v.w = __expf(v.w - rmax);
    reinterpret_cast<float4*>(rowbuf)[g] = v;
    lsum += v.x + v.y + v.z + v.w;
  }
#pragma unroll
  for (int m = 32; m >= 1; m >>= 1) lsum += __shfl_xor(lsum, m, 64);
  if ((tid & 63) == 0) red[4 + (tid >> 6)] = lsum;
  __syncthreads();
  const float inv = 1.0f / (red[4] + red[5] + red[6] + red[7]);

  bf16* dst = P + (size_t)r * SEQ;
  for (int g = tid; g < nw4; g += 256) {
    float4 v = reinterpret_cast<const float4*>(rowbuf)[g];
    bf16x4v o;
    o[0] = (bf16)(v.x * inv);
    o[1] = (bf16)(v.y * inv);
    o[2] = (bf16)(v.z * inv);
    o[3] = (bf16)(v.w * inv);
    *reinterpret_cast<bf16x4v*>(dst + g * 4) = o;
  }
}

// ---------------- out = P @ V, split-K, ALL chunks -> bf16 partials -----------
// grid 244 = 61 chunk-slots x 4 bj, XCD-swizzled. nch(bi)=ceil((bi+1)*4/10),
// <=10 K-tiles per chunk. Every chunk stores a bf16 partial tile (244 slots x
// 128KB = 30.5MB in the freed Sc region). reduce_kernel sums all partials and
// writes Out exactly once (no RMW, covers every element).
__device__ __constant__ int kNch[16]  = {1, 1, 2, 2, 2, 3, 3, 4, 4, 4, 5, 5, 6, 6, 6, 7};
__device__ __constant__ int kPref[16] = {0, 1, 2, 4, 6, 8, 11, 14, 18, 22, 26, 31, 36, 42, 48, 54};

__global__ __launch_bounds__(512, 2) void pv_kernel(const bf16* __restrict__ P,
                                                    const bf16* __restrict__ Vt,
                                                    bf16* __restrict__ Par) {
  extern __shared__ char lds[];
  const int l = xcd_swz(blockIdx.x, 244);
  const int bj = l & 3;
  int c = l >> 2, bi = 0;
  for (;;) {
    const int nch = kNch[bi];
    if (c < nch) break;
    c -= nch; ++bi;
  }
  const int nch = kNch[bi];
  const int Ti = (bi + 1) * 4;
  const int base = Ti / nch, rem = Ti % nch;
  const int kt0 = c * base + imin(c, rem);
  const int ktn = base + (c < rem ? 1 : 0);
  ACC256_INIT();
  gemm256_core(P, Vt, SEQ, SEQ, bi * 256, bj * 256, kt0, ktn, acc, lds);
  EPI_BASES();
  // bf16 partial tile, row-major 256x256
  const int slot = (kPref[bi] + c) * 4 + bj;
  bf16* Pp = Par + (size_t)slot * 65536;
#pragma unroll
  for (int mh = 0; mh < 2; ++mh)
#pragma unroll
    for (int nh = 0; nh < 2; ++nh)
#pragma unroll
      for (int mt = 0; mt < 4; ++mt)
#pragma unroll
        for (int nt = 0; nt < 2; ++nt)
#pragma unroll
          for (int j = 0; j < 4; ++j)
            Pp[(rb + mh * 64 + mt * 16 + j) * 256 + (cb + nh * 32 + nt * 16)] =
                (bf16)acc[mh][nh][mt][nt][j];
}

// ---------------- reduction: Out[tile] = sum of its bf16 partials -------------
// grid 64 tiles x 64 sub-blocks = 4096, 256 thr, 4 elems/thread. Pure write
// (no RMW) -- covers all of Out.
__global__ __launch_bounds__(256) void reduce_kernel(const bf16* __restrict__ Par,
                                                     float* __restrict__ Out) {
  const int blk = blockIdx.x;
  const int t2 = blk >> 6, sub = blk & 63;
  const int bi = t2 >> 2, bj = t2 & 3;
  const int npart = kNch[bi];                 // 1..7
  const int pb = kPref[bi] * 4 + bj;          // partial c at slot pb + c*4
  const int elem = sub * 1024 + threadIdx.x * 4;
  const int r = elem >> 8, cc = elem & 255;
  float4 o = make_float4(0.f, 0.f, 0.f, 0.f);
  for (int p = 0; p < npart; ++p) {
    const bf16x4v v = *reinterpret_cast<const bf16x4v*>(Par + (size_t)(pb + p * 4) * 65536 + elem);
    o.x += (float)v[0]; o.y += (float)v[1]; o.z += (float)v[2]; o.w += (float)v[3];
  }
  *reinterpret_cast<float4*>(Out + (size_t)(bi * 256 + r) * DOUT + bj * 256 + cc) = o;
}

extern "C" void kernel_launch(void* const* d_in, const int* in_sizes, int n_in,
                              void* d_out, int out_size, void* d_ws, size_t ws_size,
                              hipStream_t stream) {
  const float* x  = (const float*)d_in[0];
  const float* Wq = (const float*)d_in[1];
  const float* Wk = (const float*)d_in[2];
  const float* Wv = (const float*)d_in[3];
  float* Out = (float*)d_out;

  char* base = (char*)d_ws;
  bf16* xb   = (bf16*)(base + 0);          //  8 MB [4096x1024]
  bf16* wqb  = (bf16*)(base + 8388608);    //  2 MB
  bf16* wkb  = (bf16*)(base + 10485760);   //  2 MB
  bf16* wvb  = (bf16*)(base + 12582912);   //  2 MB
  bf16* Qb   = (bf16*)(base + 14680064);   //  8 MB
  bf16* Kb   = (bf16*)(base + 23068672);   //  8 MB
  bf16* Vtb  = (bf16*)(base + 31457280);   //  8 MB [1024x4096] transposed
  bf16* Scb  = (bf16*)(base + 39845888);   // 32 MB [4096x4096] bf16 scores
  bf16* Par  = (bf16*)(base + 73400320);   // 30.5 MB: pv bf16 partials (244 slots)
  bf16* P    = (bf16*)(base + 106954752);  // 32 MB [4096x4096] bf16
  // total ws use unchanged: 140,509,184 bytes

  (void)hipFuncSetAttribute((const void*)qk_kernel,
                            hipFuncAttributeMaxDynamicSharedMemorySize, 147456);
  (void)hipFuncSetAttribute((const void*)scores_v_kernel,
                            hipFuncAttributeMaxDynamicSharedMemorySize, 131072);
  (void)hipFuncSetAttribute((const void*)pv_kernel,
                            hipFuncAttributeMaxDynamicSharedMemorySize, 131072);

  cast_all_kernel<<<3584, 256, 0, stream>>>(x, Wq, Wk, Wv, xb, wqb, wkb, wvb);

  qk_kernel<<<256, 512, 147456, stream>>>(xb, wqb, wkb, Qb, Kb);
  scores_v_kernel<<<200, 512, 131072, stream>>>(Qb, Kb, Scb, xb, wvb, Vtb);
  softmax_kernel<<<SEQ, 256, 0, stream>>>(Scb, P);
  pv_kernel<<<244, 512, 131072, stream>>>(P, Vtb, Par);
  reduce_kernel<<<4096, 256, 0, stream>>>(Par, Out);
}